// Round 15
// baseline (658.654 us; speedup 1.0000x reference)
//
#include <hip/hip_runtime.h>
#include <math.h>

#define N0    4096
#define CIN   128
#define HID   256
#define COUTC 128
#define K1P   3277   // ceil(0.8*4096)
#define K2P   1967   // ceil(0.6*3277)
#define LD3   1968   // K2P padded to 4-float rows
#define KI2   3328   // K1P padded to mult of 64
#define KI3   1984   // K2P padded to mult of 64
#define DNUM  5      // digit planes, base-128 -> 35 bits

typedef __attribute__((ext_vector_type(4))) int i32x4;

__device__ __forceinline__ void gl2lds16(const void* g, void* l) {
  __builtin_amdgcn_global_load_lds((const __attribute__((address_space(1))) void*)g,
                                   (__attribute__((address_space(3))) void*)l, 16, 0, 0);
}

// ---------------- build / elementwise ----------------

__global__ void k_zero32(float* __restrict__ p, size_t n) {
  size_t i = (size_t)blockIdx.x * blockDim.x + threadIdx.x;
  size_t st = (size_t)gridDim.x * blockDim.x;
  for (; i < n; i += st) p[i] = 0.0f;
}

// adjacency built directly as i8 counts via u32-word atomics (counts << 255: no carry)
__global__ void k_build_adj8(const int* __restrict__ ei, unsigned* __restrict__ A, int E, int n) {
  int e = blockIdx.x * blockDim.x + threadIdx.x;
  if (e < E) {
    size_t byte = (size_t)ei[E + e] * n + ei[e];
    atomicAdd(&A[byte >> 2], 1u << (8 * (byte & 3)));
  }
}

// i8 square transpose (n mult of 64), multi-plane via blockIdx.z, per-plane diag fold
__global__ __launch_bounds__(256) void k_transpose_i8s(
    const char* __restrict__ A, char* __restrict__ BT, int n, size_t splane,
    int fold0, int fold1) {
  __shared__ char sm[64][68];
  const char* src = A + blockIdx.z * splane;
  char* dst = BT + blockIdx.z * splane;
  const int fold = blockIdx.z ? fold1 : fold0;
  const int t = threadIdx.x;
  const int r0 = blockIdx.y * 64, c0 = blockIdx.x * 64;
  const int rr = t >> 2, cs = (t & 3) * 16;
  {
    int4 v = *(const int4*)&src[(size_t)(r0 + rr) * n + c0 + cs];
    char* vb = (char*)&v;
#pragma unroll
    for (int j = 0; j < 16; ++j) sm[cs + j][rr] = vb[j];
  }
  __syncthreads();
  const int cc = t >> 2, rs = (t & 3) * 16;
  const int orow = c0 + cc;
  char o[16];
#pragma unroll
  for (int q = 0; q < 16; ++q) {
    char v = sm[cc][rs + q];
    if (r0 + rs + q == orow) v = (char)(v + fold);
    o[q] = v;
  }
  *(int4*)&dst[(size_t)orow * n + r0 + rs] = *(int4*)&o[0];
}

// -------- i8 pipelined augment: 3-buffer, counted-vmcnt (T4), raw barriers --------
template <int MODE>
__global__ __launch_bounds__(256) void k_aug_pipe8(
    const char* __restrict__ Asrc, const char* __restrict__ Btsrc,
    const int* __restrict__ perm, const char* __restrict__ zrow,
    int K, int ldk,
    char* __restrict__ O, size_t plane, int ldo,
    int M, int N)
{
  __shared__ __align__(16) char Ls[3][2][8192];  // 48 KB, 3-deep
  const int tid = threadIdx.x;
  const int wave = tid >> 6, lane = tid & 63;
  const int wr = wave >> 1, wc = wave & 1;
  const int brow = blockIdx.y * 128, bcol = blockIdx.x * 128;
  const int lr = lane & 15, ko = (lane >> 4) * 16;
  const int koff = (lane & 3) * 16;

  const char* pA[2];
  const char* pB[2];
#pragma unroll
  for (int c = 0; c < 2; ++c) {
    int r = (c * 4 + wave) * 16 + (lane >> 2);
    int ra = brow + r, rb = bcol + r;
    int ia, ib;
    if (MODE == 0) { ia = ra; ib = rb; }
    else {
      ia = (ra < M) ? perm[ra] : -1;
      ib = (rb < N) ? perm[rb] : -1;
    }
    pA[c] = (ia >= 0) ? Asrc + (size_t)ia * ldk : zrow;
    pB[c] = (ib >= 0) ? Btsrc + (size_t)ib * ldk : zrow;
  }

  i32x4 acc[4][4];
#pragma unroll
  for (int m = 0; m < 4; ++m)
#pragma unroll
    for (int n = 0; n < 4; ++n) acc[m][n] = (i32x4){0, 0, 0, 0};

  auto STAGE = [&](int buf, int kt) {  // 4 gl2lds16 per thread
#pragma unroll
    for (int c = 0; c < 2; ++c) {
      int f = c * 4 + wave;
      gl2lds16(pA[c] + kt + koff, &Ls[buf][0][f * 1024]);
      gl2lds16(pB[c] + kt + koff, &Ls[buf][1][f * 1024]);
    }
  };

  STAGE(0, 0);
  if (64 < K) STAGE(1, 64);
  int cur = 0;
  for (int kt = 0; kt < K; kt += 64) {
    // wait only for buf[cur]'s 4 loads; keep next stage's 4 in flight across barrier
    if (kt + 64 < K) { asm volatile("s_waitcnt vmcnt(4)" ::: "memory"); }
    else             { asm volatile("s_waitcnt vmcnt(0)" ::: "memory"); }
    __builtin_amdgcn_s_barrier();
    asm volatile("" ::: "memory");
    if (kt + 128 < K) {
      int nb = cur + 2; if (nb >= 3) nb -= 3;
      STAGE(nb, kt + 128);
    }
    i32x4 a0[4], b0[4];
#pragma unroll
    for (int m = 0; m < 4; ++m) a0[m] = *(const i32x4*)&Ls[cur][0][(wr * 64 + m * 16 + lr) * 64 + ko];
#pragma unroll
    for (int n = 0; n < 4; ++n) b0[n] = *(const i32x4*)&Ls[cur][1][(wc * 64 + n * 16 + lr) * 64 + ko];
#pragma unroll
    for (int m = 0; m < 4; ++m)
#pragma unroll
      for (int n = 0; n < 4; ++n)
        acc[m][n] = __builtin_amdgcn_mfma_i32_16x16x64_i8(a0[m], b0[n], acc[m][n], 0, 0, 0);
    cur = (cur + 1 == 3) ? 0 : cur + 1;
  }

#pragma unroll
  for (int m = 0; m < 4; ++m)
#pragma unroll
    for (int n = 0; n < 4; ++n)
#pragma unroll
      for (int q = 0; q < 4; ++q) {
        int grow = brow + wr * 64 + m * 16 + (lane >> 4) * 4 + q;
        int gcol = bcol + wc * 64 + n * 16 + lr;
        int v = acc[m][n][q];
        if (MODE == 0) {
          if (grow == gcol) v = 0;
          O[(size_t)grow * ldo + gcol] = (char)v;
        } else {
          if (grow >= M || gcol >= N || grow == gcol) v = 0;
          O[(size_t)grow * ldo + gcol] = (char)(v >> 7);
          O[plane + (size_t)grow * ldo + gcol] = (char)(v & 127);
        }
      }
}

// aug3 (i8): A3 ~= 16384 HH' + 128 (HL'+LH'); 2-buffer syncthreads (64KB, 2 blocks/CU).
__global__ __launch_bounds__(512) void k_aug3_pipe8(
    const char* __restrict__ S, const char* __restrict__ ST,
    const int* __restrict__ perm, const char* __restrict__ zrow,
    int Kpad, float* __restrict__ Cf, unsigned* __restrict__ amax,
    int M, int N, int ldcp)
{
  __shared__ __align__(16) char Ls[2][4][8192];
  const int tid = threadIdx.x;
  const int wave = tid >> 6, lane = tid & 63;
  const int wr = wave >> 1, wc = wave & 1;
  const int brow = blockIdx.y * 128, bcol = blockIdx.x * 128;
  const int lr = lane & 15, ko = (lane >> 4) * 16;
  const int koff = (lane & 3) * 16;
  const size_t plane = (size_t)Kpad * Kpad;

  const char *pAh, *pAl, *pBh, *pBl;
  {
    int r = (wave << 4) + (lane >> 2);
    int ra = brow + r, rb = bcol + r;
    int ia = (ra < M) ? perm[ra] : -1;
    int ib = (rb < N) ? perm[rb] : -1;
    pAh = (ia >= 0) ? S + (size_t)ia * Kpad : zrow;
    pAl = (ia >= 0) ? S + plane + (size_t)ia * Kpad : zrow;
    pBh = (ib >= 0) ? ST + (size_t)ib * Kpad : zrow;
    pBl = (ib >= 0) ? ST + plane + (size_t)ib * Kpad : zrow;
  }

  i32x4 hh[2][4], mid[2][4];
#pragma unroll
  for (int m = 0; m < 2; ++m)
#pragma unroll
    for (int n = 0; n < 4; ++n) {
      hh[m][n] = (i32x4){0, 0, 0, 0};
      mid[m][n] = (i32x4){0, 0, 0, 0};
    }

  auto STAGE = [&](int buf, int kt) {
    int f = wave * 1024;
    gl2lds16(pAh + kt + koff, &Ls[buf][0][f]);
    gl2lds16(pBh + kt + koff, &Ls[buf][1][f]);
    gl2lds16(pAl + kt + koff, &Ls[buf][2][f]);
    gl2lds16(pBl + kt + koff, &Ls[buf][3][f]);
  };

  STAGE(0, 0);
  __syncthreads();
  int cur = 0;
  for (int kt = 0; kt < Kpad; kt += 64) {
    if (kt + 64 < Kpad) STAGE(cur ^ 1, kt + 64);
    i32x4 ah[2], al[2], bh[4], bl[4];
#pragma unroll
    for (int m = 0; m < 2; ++m) {
      ah[m] = *(const i32x4*)&Ls[cur][0][(wr * 32 + m * 16 + lr) * 64 + ko];
      al[m] = *(const i32x4*)&Ls[cur][2][(wr * 32 + m * 16 + lr) * 64 + ko];
    }
#pragma unroll
    for (int n = 0; n < 4; ++n) {
      bh[n] = *(const i32x4*)&Ls[cur][1][(wc * 64 + n * 16 + lr) * 64 + ko];
      bl[n] = *(const i32x4*)&Ls[cur][3][(wc * 64 + n * 16 + lr) * 64 + ko];
    }
#pragma unroll
    for (int m = 0; m < 2; ++m)
#pragma unroll
      for (int n = 0; n < 4; ++n) {
        hh[m][n]  = __builtin_amdgcn_mfma_i32_16x16x64_i8(ah[m], bh[n], hh[m][n], 0, 0, 0);
        mid[m][n] = __builtin_amdgcn_mfma_i32_16x16x64_i8(ah[m], bl[n], mid[m][n], 0, 0, 0);
        mid[m][n] = __builtin_amdgcn_mfma_i32_16x16x64_i8(al[m], bh[n], mid[m][n], 0, 0, 0);
      }
    __syncthreads();
    cur ^= 1;
  }

  float mloc = 0.0f;
#pragma unroll
  for (int m = 0; m < 2; ++m)
#pragma unroll
    for (int n = 0; n < 4; ++n)
#pragma unroll
      for (int q = 0; q < 4; ++q) {
        int grow = brow + wr * 32 + m * 16 + (lane >> 4) * 4 + q;
        int gcol = bcol + wc * 64 + n * 16 + lr;
        if (grow < M && gcol < ldcp) {
          float v = 16384.0f * (float)hh[m][n][q] + 128.0f * (float)mid[m][n][q];
          if (gcol >= N || grow == gcol) v = 0.0f;
          Cf[(size_t)grow * ldcp + gcol] = v;
          mloc = fmaxf(mloc, v);
        }
      }
  __syncthreads();
  float* red = (float*)&Ls[0][0][0];
  red[tid] = mloc;
  __syncthreads();
  for (int st = 256; st > 0; st >>= 1) {
    if (tid < st) red[tid] = fmaxf(red[tid], red[tid + st]);
    __syncthreads();
  }
  if (tid == 0) atomicMax(amax, __builtin_bit_cast(unsigned, red[0]));
}

// ---------------- f64 x@W (32x64 tiles); TX = float/double; optional row-gather*val ----------------

template <typename TX, int GATHER>
__global__ __launch_bounds__(256) void k_gemm_xw32(
    const TX* __restrict__ X, const int* __restrict__ perm, const double* __restrict__ vals,
    const float* __restrict__ W, double* __restrict__ C,
    int M, int N, int K, unsigned* __restrict__ rst) {
  if (blockIdx.x == 0 && blockIdx.y == 0 && threadIdx.x == 0 && threadIdx.y == 0 && rst) *rst = 0u;
  __shared__ double As[16][32];
  __shared__ double Bs[16][64];
  const int tx = threadIdx.x, ty = threadIdx.y;
  const int tid = ty * 16 + tx;
  const int brow = blockIdx.y * 32, bcol = blockIdx.x * 64;
  const int lac = tid & 15, lar = tid >> 4;
  const int lbc = tid & 63, lbr = tid >> 6;

  int srow[2];
  double sval[2];
#pragma unroll
  for (int rr = 0; rr < 2; ++rr) {
    int gr = brow + lar + rr * 16;
    if (GATHER) {
      srow[rr] = (gr < M) ? perm[gr] : 0;
      sval[rr] = (gr < M) ? vals[gr] : 0.0;
    } else {
      srow[rr] = gr;
      sval[rr] = 1.0;
    }
  }

  double acc[2][4];
#pragma unroll
  for (int i = 0; i < 2; ++i)
#pragma unroll
    for (int j = 0; j < 4; ++j) acc[i][j] = 0.0;

  for (int kt = 0; kt < K; kt += 16) {
#pragma unroll
    for (int rr = 0; rr < 2; ++rr) {
      int gr = brow + lar + rr * 16;
      int gk = kt + lac;
      double v = 0.0;
      if (gr < M && gk < K) {
        v = (double)X[(size_t)srow[rr] * K + gk];
        if (GATHER) v *= sval[rr];
      }
      As[lac][lar + rr * 16] = v;
    }
#pragma unroll
    for (int rr = 0; rr < 4; ++rr) {
      int br = lbr + rr * 4;
      int gk = kt + br, gc = bcol + lbc;
      Bs[br][lbc] = (gk < K && gc < N) ? (double)W[(size_t)gk * N + gc] : 0.0;
    }
    __syncthreads();
#pragma unroll
    for (int kk = 0; kk < 16; ++kk) {
      double a[2], b[4];
#pragma unroll
      for (int i = 0; i < 2; ++i) a[i] = As[kk][ty * 2 + i];
#pragma unroll
      for (int j = 0; j < 4; ++j) b[j] = Bs[kk][tx * 4 + j];
#pragma unroll
      for (int i = 0; i < 2; ++i)
#pragma unroll
        for (int j = 0; j < 4; ++j) acc[i][j] = fma(a[i], b[j], acc[i][j]);
    }
    __syncthreads();
  }
#pragma unroll
  for (int i = 0; i < 2; ++i) {
    int gr = brow + ty * 2 + i;
    if (gr >= M) continue;
#pragma unroll
    for (int j = 0; j < 4; ++j) {
      int gc = bcol + tx * 4 + j;
      if (gc >= N) continue;
      C[(size_t)gr * N + gc] = acc[i][j];
    }
  }
}

// ---------------- digit machinery (i8, base-128) ----------------

__global__ void k_wmax(const double* __restrict__ t, const double* __restrict__ dinv,
                       unsigned* __restrict__ wmax, int K, int N) {
  __shared__ float red[256];
  float mx = 0.0f;
  int tot = K * N;
  for (int i = blockIdx.x * 256 + threadIdx.x; i < tot; i += gridDim.x * 256) {
    double w = dinv[i / N] * t[i];
    mx = fmaxf(mx, (float)fabs(w));
  }
  red[threadIdx.x] = mx;
  __syncthreads();
  for (int st = 128; st > 0; st >>= 1) {
    if (threadIdx.x < st) red[threadIdx.x] = fmaxf(red[threadIdx.x], red[threadIdx.x + st]);
    __syncthreads();
  }
  if (threadIdx.x == 0) atomicMax(wmax, __builtin_bit_cast(unsigned, red[0]));
}

template <int D>
__global__ __launch_bounds__(256) void k_digitize8(
    const double* __restrict__ t, const double* __restrict__ dinv,
    const unsigned* __restrict__ wmax, char* __restrict__ wdT,
    int K, int Kpad, int N) {
  __shared__ char sm[D][64][68];
  const int tid = threadIdx.x;
  const int k0 = blockIdx.x * 64, n0 = blockIdx.y * 64;
  float wm = __builtin_bit_cast(float, *wmax);
  double sc = (wm > 0.0f) ? scalbn(1.0, -(ilogbf(wm) + 2)) : 0.0;
  const int kk = tid >> 2, ns = (tid & 3) * 16;
  int k = k0 + kk;
  double dv = (k < K) ? dinv[k] : 0.0;
#pragma unroll
  for (int j = 0; j < 16; ++j) {
    int n = n0 + ns + j;
    double w = (k < K) ? dv * t[(size_t)k * N + n] : 0.0;
    double r = w * sc;
#pragma unroll
    for (int d = 0; d < D; ++d) {
      double rm = r * 128.0;
      double m = rint(rm);
      sm[d][kk][ns + j] = (char)(int)m;
      r = rm - m;
    }
  }
  __syncthreads();
  const int nn = tid >> 2, ks = (tid & 3) * 16;
  const size_t PS = (size_t)N * Kpad;
#pragma unroll
  for (int d = 0; d < D; ++d) {
    char o[16];
#pragma unroll
    for (int j = 0; j < 16; ++j) o[j] = sm[d][ks + j][nn];
    *(int4*)&wdT[d * PS + (size_t)(n0 + nn) * Kpad + k0 + ks] = *(int4*)&o[0];
  }
}

// A3p f32 (nonneg, values-path) -> scaled 14-bit base-128 i8 planes.
__global__ void k_splitA8s(const float* __restrict__ A, int M, int ldsrc,
                           const unsigned* __restrict__ amax,
                           char* __restrict__ S, int Kpad) {
  int r = blockIdx.x;
  const size_t plane = (size_t)Kpad * Kpad;
  float am = __builtin_bit_cast(float, *amax);
  float s13 = (am > 0.0f) ? scalbnf(1.0f, 13 - (ilogbf(am) + 1)) : 0.0f;
  for (int c4 = threadIdx.x * 4; c4 < Kpad; c4 += blockDim.x * 4) {
    float v[4] = {0.f, 0.f, 0.f, 0.f};
    if (r < M && c4 < ldsrc) *(float4*)v = *(const float4*)(A + (size_t)r * ldsrc + c4);
    unsigned hw = 0, lw = 0;
#pragma unroll
    for (int q = 0; q < 4; ++q) {
      int iv = (int)rintf(v[q] * s13);
      int h = iv >> 7, l = iv - (h << 7);
      hw |= ((unsigned)(unsigned char)(char)h) << (8 * q);
      lw |= ((unsigned)(unsigned char)(char)l) << (8 * q);
    }
    *(unsigned*)(S + (size_t)r * Kpad + c4) = hw;
    *(unsigned*)(S + plane + (size_t)r * Kpad + c4) = lw;
  }
}

// P[Mp][Neff] i32 = A @ wdT^T — 3-buffer counted-vmcnt i8 GEMM, exact.
__global__ __launch_bounds__(256) void k_axw_pipe8(
    const char* __restrict__ Asrc, const char* __restrict__ Bsrc,
    int Kpad, int* __restrict__ P, int Neff)
{
  __shared__ __align__(16) char Ls[3][2][8192];  // 48 KB, 3-deep
  const int tid = threadIdx.x;
  const int wave = tid >> 6, lane = tid & 63;
  const int wr = wave >> 1, wc = wave & 1;
  const int brow = blockIdx.y * 128, bcol = blockIdx.x * 128;
  const int lr = lane & 15, ko = (lane >> 4) * 16;
  const int koff = (lane & 3) * 16;

  const char* pA[2];
  const char* pB[2];
#pragma unroll
  for (int c = 0; c < 2; ++c) {
    int r = (c * 4 + wave) * 16 + (lane >> 2);
    pA[c] = Asrc + (size_t)(brow + r) * Kpad;
    pB[c] = Bsrc + (size_t)(bcol + r) * Kpad;
  }

  i32x4 acc[4][4];
#pragma unroll
  for (int m = 0; m < 4; ++m)
#pragma unroll
    for (int n = 0; n < 4; ++n) acc[m][n] = (i32x4){0, 0, 0, 0};

  auto STAGE = [&](int buf, int kt) {  // 4 gl2lds16 per thread
#pragma unroll
    for (int c = 0; c < 2; ++c) {
      int f = c * 4 + wave;
      gl2lds16(pA[c] + kt + koff, &Ls[buf][0][f * 1024]);
      gl2lds16(pB[c] + kt + koff, &Ls[buf][1][f * 1024]);
    }
  };

  STAGE(0, 0);
  if (64 < Kpad) STAGE(1, 64);
  int cur = 0;
  for (int kt = 0; kt < Kpad; kt += 64) {
    if (kt + 64 < Kpad) { asm volatile("s_waitcnt vmcnt(4)" ::: "memory"); }
    else                { asm volatile("s_waitcnt vmcnt(0)" ::: "memory"); }
    __builtin_amdgcn_s_barrier();
    asm volatile("" ::: "memory");
    if (kt + 128 < Kpad) {
      int nb = cur + 2; if (nb >= 3) nb -= 3;
      STAGE(nb, kt + 128);
    }
    i32x4 a0[4], b0[4];
#pragma unroll
    for (int m = 0; m < 4; ++m) a0[m] = *(const i32x4*)&Ls[cur][0][(wr * 64 + m * 16 + lr) * 64 + ko];
#pragma unroll
    for (int n = 0; n < 4; ++n) b0[n] = *(const i32x4*)&Ls[cur][1][(wc * 64 + n * 16 + lr) * 64 + ko];
#pragma unroll
    for (int m = 0; m < 4; ++m)
#pragma unroll
      for (int n = 0; n < 4; ++n)
        acc[m][n] = __builtin_amdgcn_mfma_i32_16x16x64_i8(a0[m], b0[n], acc[m][n], 0, 0, 0);
    cur = (cur + 1 == 3) ? 0 : cur + 1;
  }

#pragma unroll
  for (int m = 0; m < 4; ++m)
#pragma unroll
    for (int n = 0; n < 4; ++n)
#pragma unroll
      for (int q = 0; q < 4; ++q) {
        int grow = brow + wr * 64 + m * 16 + (lane >> 4) * 4 + q;
        int gcol = bcol + wc * 64 + n * 16 + lr;
        P[(size_t)grow * Neff + gcol] = acc[m][n][q];
      }
}

// fused reduce_y + gcn_fin (+ optional per-row scores, + optional f32 output with tail zero)
template <int SCORES, int OUT32>
__global__ void k_reduce_fin(const int* __restrict__ P, const unsigned* __restrict__ wmax,
                             const unsigned* __restrict__ amax,
                             const double* __restrict__ t, const double* __restrict__ dinv,
                             const float* __restrict__ bias, double* __restrict__ out,
                             float* __restrict__ fout, int nvals, int total,
                             const float* __restrict__ p, double* __restrict__ scv,
                             unsigned* __restrict__ rst,
                             int Neff, int N, int D, int M0pad, int nplane,
                             double w0, double w1, int relu) {
  int m = blockIdx.x;
  if (SCORES) { if (m == 0 && threadIdx.x == 0 && rst) *rst = 0u; }
  float wm = __builtin_bit_cast(float, *wmax);
  double s0 = w0, s1 = w1;
  bool zero = (wm <= 0.0f);
  if (amax) {
    float am = __builtin_bit_cast(float, *amax);
    if (am > 0.0f) {
      int EA = ilogbf(am) + 1;
      s0 = scalbn(w0, EA - 13);
      s1 = scalbn(w1, EA - 13);
    } else zero = true;
  }
  int Ep = zero ? 0 : (ilogbf(wm) + 2);
  double d = dinv[m];
  __shared__ double red[256], red2[256];
  double sdot = 0.0, sp2 = 0.0;
  for (int n = threadIdx.x; n < N; n += blockDim.x) {
    double acc = 0.0;
    if (!zero) {
      for (int dd = 0; dd < D; ++dd) {
        double v = s0 * (double)P[(size_t)m * Neff + dd * N + n];
        if (nplane == 2) v += s1 * (double)P[(size_t)(M0pad + m) * Neff + dd * N + n];
        acc += scalbn(v, Ep - 7 * (dd + 1));
      }
    }
    double v = d * (acc + 2.0 * d * t[(size_t)m * N + n]) + (double)bias[n];
    if (relu) v = v > 0.0 ? v : 0.0;
    if (OUT32) fout[(size_t)m * N + n] = (float)v;
    else out[(size_t)m * N + n] = v;
    if (SCORES) {
      double pv = (double)p[n];
      sdot += v * pv;
      sp2 += pv * pv;
    }
  }
  if (OUT32) {
    if (m == 0)
      for (int i = nvals + threadIdx.x; i < total; i += blockDim.x) fout[i] = 0.0f;
  }
  if (SCORES) {
    red[threadIdx.x] = sdot;
    red2[threadIdx.x] = sp2;
    __syncthreads();
    for (int st = 128; st > 0; st >>= 1) {
      if (threadIdx.x < st) {
        red[threadIdx.x] += red[threadIdx.x + st];
        red2[threadIdx.x] += red2[threadIdx.x + st];
      }
      __syncthreads();
    }
    if (threadIdx.x == 0) scv[m] = tanh(red[0] / sqrt(red2[0]));
  }
}

// ---------------- GCN tail / pooling ----------------

template <typename TA>
__device__ __forceinline__ float a_as_f32(TA v);
template <> __device__ __forceinline__ float a_as_f32<char>(char v) { return (float)v; }
template <> __device__ __forceinline__ float a_as_f32<float>(float v) { return v; }

template <typename TA>
__global__ void k_degdinv(const TA* __restrict__ A, int lda, double* __restrict__ dinv, int n,
                          unsigned* __restrict__ rst0, unsigned* __restrict__ rst1) {
  if (blockIdx.x == 0 && threadIdx.x == 0) {
    if (rst0) *rst0 = 0u;
    if (rst1) *rst1 = 0u;
  }
  __shared__ double red[256];
  int row = blockIdx.x;
  double s = 0.0;
  for (int j = threadIdx.x; j < n; j += 256) s += (double)a_as_f32<TA>(A[(size_t)row * lda + j]);
  red[threadIdx.x] = s;
  __syncthreads();
  for (int st = 128; st > 0; st >>= 1) {
    if (threadIdx.x < st) red[threadIdx.x] += red[threadIdx.x + st];
    __syncthreads();
  }
  if (threadIdx.x == 0) {
    double deg = red[0] + 2.0;
    dinv[row] = (deg > 0.0) ? 1.0 / sqrt(deg) : 0.0;
  }
}

// dinv from 2-plane i8 (128*h + l): exact integer row sums.
__global__ void k_degdinv2p(const char* __restrict__ S, int Kpad, double* __restrict__ dinv,
                            int n, unsigned* __restrict__ rst0) {
  if (blockIdx.x == 0 && threadIdx.x == 0 && rst0) *rst0 = 0u;
  __shared__ double red[256];
  const size_t plane = (size_t)Kpad * Kpad;
  int row = blockIdx.x;
  const char* h = S + (size_t)row * Kpad;
  const char* l = S + plane + (size_t)row * Kpad;
  long s = 0;
  for (int j = threadIdx.x; j < n; j += 256) s += 128 * (long)h[j] + (long)l[j];
  red[threadIdx.x] = (double)s;
  __syncthreads();
  for (int st = 128; st > 0; st >>= 1) {
    if (threadIdx.x < st) red[threadIdx.x] += red[threadIdx.x + st];
    __syncthreads();
  }
  if (threadIdx.x == 0) {
    double deg = red[0] + 2.0;
    dinv[row] = (deg > 0.0) ? 1.0 / sqrt(deg) : 0.0;
  }
}

// rank-count top-k (bitwise-identical to full sort under (score desc, idx asc))
__global__ __launch_bounds__(256) void k_topk_rank(
    const double* __restrict__ sc, int n, int k,
    int* __restrict__ perm, double* __restrict__ vals) {
  __shared__ int red[256];
  const int i = blockIdx.x;
  const double si = sc[i];
  int cnt = 0;
  for (int j = threadIdx.x; j < n; j += 256) {
    double sj = sc[j];
    if (sj > si || (sj == si && j < i)) ++cnt;
  }
  red[threadIdx.x] = cnt;
  __syncthreads();
  for (int st = 128; st > 0; st >>= 1) {
    if (threadIdx.x < st) red[threadIdx.x] += red[threadIdx.x + st];
    __syncthreads();
  }
  if (threadIdx.x == 0) {
    int rank = red[0];
    if (rank < k) { perm[rank] = i; vals[rank] = si; }
  }
}

__global__ void k_sentinel(float* __restrict__ out, int total) {
  int i = blockIdx.x * blockDim.x + threadIdx.x;
  int st = gridDim.x * blockDim.x;
  for (; i < total; i += st) out[i] = 1e30f;
}

// ---------------- driver ----------------

extern "C" void kernel_launch(void* const* d_in, const int* in_sizes, int n_in,
                              void* d_out, int out_size, void* d_ws, size_t ws_size,
                              hipStream_t stream) {
  const float* x0f  = (const float*)d_in[0];
  const int*   ei   = (const int*)d_in[1];
  const float* W0   = (const float*)d_in[2];
  const float* b0   = (const float*)d_in[3];
  const float* W1   = (const float*)d_in[4];
  const float* b1   = (const float*)d_in[5];
  const float* W2   = (const float*)d_in[6];
  const float* b2   = (const float*)d_in[7];
  const float* p1   = (const float*)d_in[8];
  const float* p2   = (const float*)d_in[9];
  const float* Wout = (const float*)d_in[10];
  const float* bout = (const float*)d_in[11];
  const int E = in_sizes[1] / 2;

  const size_t MiB = 1ull << 20;
  if (ws_size < 160 * MiB) {
    k_sentinel<<<dim3(256), dim3(256), 0, stream>>>((float*)d_out, out_size);
    return;
  }
  char* W = (char*)d_ws;
  const size_t PL2 = (size_t)KI2 * KI2;
  // epoch A: build + aug1 (A0 built directly as i8)
  char*  A0s8  = (char*)(W + 64 * MiB);
  char*  A0s8T = (char*)(W + 80 * MiB);
  // epoch A2: gcn1
  char*  A1    = (char*)(W + 0);
  char*  A1T   = (char*)(W + 16 * MiB);
  char*  wdT1  = (char*)(W + 32 * MiB);
  int*   P1    = (int*)(W + 40 * MiB);
  // epoch B: aug2 + gcn2
  char*  A2s8  = (char*)(W + 64 * MiB);
  char*  A2s8T = (char*)(W + 86 * MiB);
  char*  wdT2  = (char*)(W + 0);
  int*   P2    = (int*)(W + 7 * MiB);
  // epoch C: aug3 + gcn3/out
  float* A3p     = (float*)(W + 108 * MiB);
  char*  A3stack = (char*)(W + 0);
  char*  wdT3    = (char*)(W + 8 * MiB);
  int*   P3      = (int*)(W + 10 * MiB);
  // features
  double* tb   = (double*)(W + 128 * MiB);
  double* xA   = (double*)(W + 144 * MiB);
  char* SM = W + (159 * MiB + 256 * 1024);
  double* dinv = (double*)(SM);
  double* sc   = (double*)(SM + 32768);
  double* vals = (double*)(SM + 65536);
  unsigned* wmax  = (unsigned*)(SM + 98304 + 128);
  unsigned* a3max = (unsigned*)(SM + 98304 + 192);
  int* perm    = (int*)(SM + 98304 + 256);
  int* permB   = (int*)(SM + 98304 + 256 + 16384);
  char* zpage  = (char*)(W + 159 * MiB + 512 * 1024);

  // ---- build A0 as i8 + transpose (+2I) ----
  k_zero32<<<dim3(8), dim3(256), 0, stream>>>((float*)zpage, 8192);
  k_zero32<<<dim3(1024), dim3(256), 0, stream>>>((float*)A0s8, (size_t)N0 * N0 / 4);
  k_build_adj8<<<dim3((E + 255) / 256), dim3(256), 0, stream>>>(ei, (unsigned*)A0s8, E, N0);
  k_transpose_i8s<<<dim3(64, 64, 1), dim3(256), 0, stream>>>(A0s8, A0s8T, N0, 0, 2, 0);

  // ---- aug1 ----
  k_aug_pipe8<0><<<dim3(32, 32), dim3(256), 0, stream>>>(
      A0s8, A0s8T, nullptr, zpage, N0, N0, A1, 0, N0, N0, N0);
  k_transpose_i8s<<<dim3(64, 64, 1), dim3(256), 0, stream>>>(A1, A1T, N0, 0, 2, 0);

  // ---- gcn1 ----
  {
    dim3 b(16, 16);
    k_gemm_xw32<float, 0><<<dim3(HID / 64, (N0 + 31) / 32), b, 0, stream>>>(
        x0f, nullptr, nullptr, W0, tb, N0, HID, CIN, nullptr);
    k_degdinv<char><<<dim3(N0), dim3(256), 0, stream>>>(A1, N0, dinv, N0, wmax, nullptr);
    k_wmax<<<dim3(256), dim3(256), 0, stream>>>(tb, dinv, wmax, N0, HID);
    k_digitize8<DNUM><<<dim3(N0 / 64, HID / 64), dim3(256), 0, stream>>>(tb, dinv, wmax, wdT1, N0, N0, HID);
    k_axw_pipe8<<<dim3(DNUM * HID / 128, N0 / 128), dim3(256), 0, stream>>>(A1, wdT1, N0, P1, DNUM * HID);
    k_reduce_fin<1, 0><<<dim3(N0), dim3(256), 0, stream>>>(
        P1, wmax, nullptr, tb, dinv, b0, xA, nullptr, 0, 0, p1, sc, nullptr,
        DNUM * HID, HID, DNUM, 0, 1, 1.0, 0.0, 1);
  }

  // ---- pool1 ----
  k_topk_rank<<<dim3(N0), dim3(256), 0, stream>>>(sc, N0, K1P, perm, vals);

  // ---- aug2 ----
  k_aug_pipe8<1><<<dim3(26, 26), dim3(256), 0, stream>>>(
      A1, A1T, perm, zpage, N0, N0, A2s8, PL2, KI2, K1P, K1P);
  k_transpose_i8s<<<dim3(52, 52, 2), dim3(256), 0, stream>>>(A2s8, A2s8T, KI2, PL2, 0, 2);

  // ---- gcn2 ----
  {
    dim3 b(16, 16);
    k_gemm_xw32<double, 1><<<dim3(HID / 64, (K1P + 31) / 32), b, 0, stream>>>(
        xA, perm, vals, W1, tb, K1P, HID, HID, nullptr);
    k_degdinv2p<<<dim3(K1P), dim3(256), 0, stream>>>(A2s8, KI2, dinv, K1P, wmax);
    k_wmax<<<dim3(256), dim3(256), 0, stream>>>(tb, dinv, wmax, K1P, HID);
    k_digitize8<DNUM><<<dim3(KI2 / 64, HID / 64), dim3(256), 0, stream>>>(tb, dinv, wmax, wdT2, K1P, KI2, HID);
    k_axw_pipe8<<<dim3(DNUM * HID / 128, 2 * KI2 / 128), dim3(256), 0, stream>>>(A2s8, wdT2, KI2, P2, DNUM * HID);
    k_reduce_fin<1, 0><<<dim3(K1P), dim3(256), 0, stream>>>(
        P2, wmax, nullptr, tb, dinv, b1, xA, nullptr, 0, 0, p2, sc, a3max,
        DNUM * HID, HID, DNUM, KI2, 2, 128.0, 1.0, 1);
  }

  // ---- pool2 ----
  k_topk_rank<<<dim3(K1P), dim3(256), 0, stream>>>(sc, K1P, K2P, permB, vals);

  // ---- aug3 ----
  k_aug3_pipe8<<<dim3(16, 16), dim3(512), 0, stream>>>(
      A2s8, A2s8T, permB, zpage, KI2, A3p, a3max, K2P, K2P, LD3);

  // ---- gcn3 ----
  {
    dim3 b(16, 16);
    k_gemm_xw32<double, 1><<<dim3(HID / 64, (K2P + 31) / 32), b, 0, stream>>>(
        xA, permB, vals, W2, tb, K2P, HID, HID, nullptr);
    k_degdinv<float><<<dim3(K2P), dim3(256), 0, stream>>>(A3p, LD3, dinv, K2P, wmax, nullptr);
    k_splitA8s<<<dim3(KI3), dim3(256), 0, stream>>>(A3p, K2P, LD3, a3max, A3stack, KI3);
    k_wmax<<<dim3(256), dim3(256), 0, stream>>>(tb, dinv, wmax, K2P, HID);
    k_digitize8<2><<<dim3(KI3 / 64, HID / 64), dim3(256), 0, stream>>>(tb, dinv, wmax, wdT3, K2P, KI3, HID);
    k_axw_pipe8<<<dim3(2 * HID / 128, 2 * KI3 / 128), dim3(256), 0, stream>>>(A3stack, wdT3, KI3, P3, 2 * HID);
    k_reduce_fin<0, 0><<<dim3(K2P), dim3(256), 0, stream>>>(
        P3, wmax, a3max, tb, dinv, b2, xA, nullptr, 0, 0, nullptr, nullptr, nullptr,
        2 * HID, HID, 2, KI3, 2, 128.0, 1.0, 1);
  }

  // ---- gcn_out ----
  {
    dim3 b(16, 16);
    k_gemm_xw32<double, 0><<<dim3(COUTC / 64, (K2P + 31) / 32), b, 0, stream>>>(
        xA, nullptr, nullptr, Wout, tb, K2P, COUTC, HID, wmax);
    k_wmax<<<dim3(256), dim3(256), 0, stream>>>(tb, dinv, wmax, K2P, COUTC);
    k_digitize8<2><<<dim3(KI3 / 64, COUTC / 64), dim3(256), 0, stream>>>(tb, dinv, wmax, wdT3, K2P, KI3, COUTC);
    k_axw_pipe8<<<dim3(2 * COUTC / 128, 2 * KI3 / 128), dim3(256), 0, stream>>>(A3stack, wdT3, KI3, P3, 2 * COUTC);
    k_reduce_fin<0, 1><<<dim3(K2P), dim3(256), 0, stream>>>(
        P3, wmax, a3max, tb, dinv, bout, nullptr, (float*)d_out, K2P * COUTC, out_size,
        nullptr, nullptr, nullptr, 2 * COUTC, COUTC, 2, KI3, 2, 128.0, 1.0, 0);
  }
}

// Round 16
// 652.483 us; speedup vs baseline: 1.0095x; 1.0095x over previous
//
#include <hip/hip_runtime.h>
#include <math.h>

#define N0    4096
#define CIN   128
#define HID   256
#define COUTC 128
#define K1P   3277   // ceil(0.8*4096)
#define K2P   1967   // ceil(0.6*3277)
#define LD3   1968   // K2P padded to 4-float rows
#define KI2   3328   // K1P padded to mult of 64
#define KI3   1984   // K2P padded to mult of 64
#define DNUM  5      // digit planes, base-128 -> 35 bits

typedef __attribute__((ext_vector_type(4))) int i32x4;

__device__ __forceinline__ void gl2lds16(const void* g, void* l) {
  __builtin_amdgcn_global_load_lds((const __attribute__((address_space(1))) void*)g,
                                   (__attribute__((address_space(3))) void*)l, 16, 0, 0);
}

// ---------------- build / elementwise ----------------

__global__ void k_zero32(float* __restrict__ p, size_t n) {
  size_t i = (size_t)blockIdx.x * blockDim.x + threadIdx.x;
  size_t st = (size_t)gridDim.x * blockDim.x;
  for (; i < n; i += st) p[i] = 0.0f;
}

// adjacency built directly as i8 counts via u32-word atomics (counts << 255: no carry)
__global__ void k_build_adj8(const int* __restrict__ ei, unsigned* __restrict__ A, int E, int n) {
  int e = blockIdx.x * blockDim.x + threadIdx.x;
  if (e < E) {
    size_t byte = (size_t)ei[E + e] * n + ei[e];
    atomicAdd(&A[byte >> 2], 1u << (8 * (byte & 3)));
  }
}

// i8 square transpose (n mult of 64), multi-plane via blockIdx.z, per-plane diag fold
__global__ __launch_bounds__(256) void k_transpose_i8s(
    const char* __restrict__ A, char* __restrict__ BT, int n, size_t splane,
    int fold0, int fold1) {
  __shared__ char sm[64][68];
  const char* src = A + blockIdx.z * splane;
  char* dst = BT + blockIdx.z * splane;
  const int fold = blockIdx.z ? fold1 : fold0;
  const int t = threadIdx.x;
  const int r0 = blockIdx.y * 64, c0 = blockIdx.x * 64;
  const int rr = t >> 2, cs = (t & 3) * 16;
  {
    int4 v = *(const int4*)&src[(size_t)(r0 + rr) * n + c0 + cs];
    char* vb = (char*)&v;
#pragma unroll
    for (int j = 0; j < 16; ++j) sm[cs + j][rr] = vb[j];
  }
  __syncthreads();
  const int cc = t >> 2, rs = (t & 3) * 16;
  const int orow = c0 + cc;
  char o[16];
#pragma unroll
  for (int q = 0; q < 16; ++q) {
    char v = sm[cc][rs + q];
    if (r0 + rs + q == orow) v = (char)(v + fold);
    o[q] = v;
  }
  *(int4*)&dst[(size_t)orow * n + r0 + rs] = *(int4*)&o[0];
}

// -------- i8 pipelined augment, 2-buffer DMA dbuf (proven round-14 structure) --------
template <int MODE>
__global__ __launch_bounds__(256) void k_aug_pipe8(
    const char* __restrict__ Asrc, const char* __restrict__ Btsrc,
    const int* __restrict__ perm, const char* __restrict__ zrow,
    int K, int ldk,
    char* __restrict__ O, size_t plane, int ldo,
    int M, int N)
{
  __shared__ __align__(16) char Ls[2][2][8192];
  const int tid = threadIdx.x;
  const int wave = tid >> 6, lane = tid & 63;
  const int wr = wave >> 1, wc = wave & 1;
  const int brow = blockIdx.y * 128, bcol = blockIdx.x * 128;
  const int lr = lane & 15, ko = (lane >> 4) * 16;
  const int koff = (lane & 3) * 16;

  const char* pA[2];
  const char* pB[2];
#pragma unroll
  for (int c = 0; c < 2; ++c) {
    int r = (c * 4 + wave) * 16 + (lane >> 2);
    int ra = brow + r, rb = bcol + r;
    int ia, ib;
    if (MODE == 0) { ia = ra; ib = rb; }
    else {
      ia = (ra < M) ? perm[ra] : -1;
      ib = (rb < N) ? perm[rb] : -1;
    }
    pA[c] = (ia >= 0) ? Asrc + (size_t)ia * ldk : zrow;
    pB[c] = (ib >= 0) ? Btsrc + (size_t)ib * ldk : zrow;
  }

  i32x4 acc[4][4];
#pragma unroll
  for (int m = 0; m < 4; ++m)
#pragma unroll
    for (int n = 0; n < 4; ++n) acc[m][n] = (i32x4){0, 0, 0, 0};

  auto STAGE = [&](int buf, int kt) {
#pragma unroll
    for (int c = 0; c < 2; ++c) {
      int f = c * 4 + wave;
      gl2lds16(pA[c] + kt + koff, &Ls[buf][0][f * 1024]);
      gl2lds16(pB[c] + kt + koff, &Ls[buf][1][f * 1024]);
    }
  };

  STAGE(0, 0);
  __syncthreads();
  int cur = 0;
  for (int kt = 0; kt < K; kt += 64) {
    if (kt + 64 < K) STAGE(cur ^ 1, kt + 64);
    i32x4 a0[4], b0[4];
#pragma unroll
    for (int m = 0; m < 4; ++m) a0[m] = *(const i32x4*)&Ls[cur][0][(wr * 64 + m * 16 + lr) * 64 + ko];
#pragma unroll
    for (int n = 0; n < 4; ++n) b0[n] = *(const i32x4*)&Ls[cur][1][(wc * 64 + n * 16 + lr) * 64 + ko];
#pragma unroll
    for (int m = 0; m < 4; ++m)
#pragma unroll
      for (int n = 0; n < 4; ++n)
        acc[m][n] = __builtin_amdgcn_mfma_i32_16x16x64_i8(a0[m], b0[n], acc[m][n], 0, 0, 0);
    __syncthreads();
    cur ^= 1;
  }

#pragma unroll
  for (int m = 0; m < 4; ++m)
#pragma unroll
    for (int n = 0; n < 4; ++n)
#pragma unroll
      for (int q = 0; q < 4; ++q) {
        int grow = brow + wr * 64 + m * 16 + (lane >> 4) * 4 + q;
        int gcol = bcol + wc * 64 + n * 16 + lr;
        int v = acc[m][n][q];
        if (MODE == 0) {
          if (grow == gcol) v = 0;
          O[(size_t)grow * ldo + gcol] = (char)v;
        } else {
          if (grow >= M || gcol >= N || grow == gcol) v = 0;
          O[(size_t)grow * ldo + gcol] = (char)(v >> 7);
          O[plane + (size_t)grow * ldo + gcol] = (char)(v & 127);
        }
      }
}

// aug3 (i8): A3 ~= 16384 HH' + 128 (HL'+LH'); 2-buffer syncthreads.
__global__ __launch_bounds__(512) void k_aug3_pipe8(
    const char* __restrict__ S, const char* __restrict__ ST,
    const int* __restrict__ perm, const char* __restrict__ zrow,
    int Kpad, float* __restrict__ Cf, unsigned* __restrict__ amax,
    int M, int N, int ldcp)
{
  __shared__ __align__(16) char Ls[2][4][8192];
  const int tid = threadIdx.x;
  const int wave = tid >> 6, lane = tid & 63;
  const int wr = wave >> 1, wc = wave & 1;
  const int brow = blockIdx.y * 128, bcol = blockIdx.x * 128;
  const int lr = lane & 15, ko = (lane >> 4) * 16;
  const int koff = (lane & 3) * 16;
  const size_t plane = (size_t)Kpad * Kpad;

  const char *pAh, *pAl, *pBh, *pBl;
  {
    int r = (wave << 4) + (lane >> 2);
    int ra = brow + r, rb = bcol + r;
    int ia = (ra < M) ? perm[ra] : -1;
    int ib = (rb < N) ? perm[rb] : -1;
    pAh = (ia >= 0) ? S + (size_t)ia * Kpad : zrow;
    pAl = (ia >= 0) ? S + plane + (size_t)ia * Kpad : zrow;
    pBh = (ib >= 0) ? ST + (size_t)ib * Kpad : zrow;
    pBl = (ib >= 0) ? ST + plane + (size_t)ib * Kpad : zrow;
  }

  i32x4 hh[2][4], mid[2][4];
#pragma unroll
  for (int m = 0; m < 2; ++m)
#pragma unroll
    for (int n = 0; n < 4; ++n) {
      hh[m][n] = (i32x4){0, 0, 0, 0};
      mid[m][n] = (i32x4){0, 0, 0, 0};
    }

  auto STAGE = [&](int buf, int kt) {
    int f = wave * 1024;
    gl2lds16(pAh + kt + koff, &Ls[buf][0][f]);
    gl2lds16(pBh + kt + koff, &Ls[buf][1][f]);
    gl2lds16(pAl + kt + koff, &Ls[buf][2][f]);
    gl2lds16(pBl + kt + koff, &Ls[buf][3][f]);
  };

  STAGE(0, 0);
  __syncthreads();
  int cur = 0;
  for (int kt = 0; kt < Kpad; kt += 64) {
    if (kt + 64 < Kpad) STAGE(cur ^ 1, kt + 64);
    i32x4 ah[2], al[2], bh[4], bl[4];
#pragma unroll
    for (int m = 0; m < 2; ++m) {
      ah[m] = *(const i32x4*)&Ls[cur][0][(wr * 32 + m * 16 + lr) * 64 + ko];
      al[m] = *(const i32x4*)&Ls[cur][2][(wr * 32 + m * 16 + lr) * 64 + ko];
    }
#pragma unroll
    for (int n = 0; n < 4; ++n) {
      bh[n] = *(const i32x4*)&Ls[cur][1][(wc * 64 + n * 16 + lr) * 64 + ko];
      bl[n] = *(const i32x4*)&Ls[cur][3][(wc * 64 + n * 16 + lr) * 64 + ko];
    }
#pragma unroll
    for (int m = 0; m < 2; ++m)
#pragma unroll
      for (int n = 0; n < 4; ++n) {
        hh[m][n]  = __builtin_amdgcn_mfma_i32_16x16x64_i8(ah[m], bh[n], hh[m][n], 0, 0, 0);
        mid[m][n] = __builtin_amdgcn_mfma_i32_16x16x64_i8(ah[m], bl[n], mid[m][n], 0, 0, 0);
        mid[m][n] = __builtin_amdgcn_mfma_i32_16x16x64_i8(al[m], bh[n], mid[m][n], 0, 0, 0);
      }
    __syncthreads();
    cur ^= 1;
  }

  float mloc = 0.0f;
#pragma unroll
  for (int m = 0; m < 2; ++m)
#pragma unroll
    for (int n = 0; n < 4; ++n)
#pragma unroll
      for (int q = 0; q < 4; ++q) {
        int grow = brow + wr * 32 + m * 16 + (lane >> 4) * 4 + q;
        int gcol = bcol + wc * 64 + n * 16 + lr;
        if (grow < M && gcol < ldcp) {
          float v = 16384.0f * (float)hh[m][n][q] + 128.0f * (float)mid[m][n][q];
          if (gcol >= N || grow == gcol) v = 0.0f;
          Cf[(size_t)grow * ldcp + gcol] = v;
          mloc = fmaxf(mloc, v);
        }
      }
  __syncthreads();
  float* red = (float*)&Ls[0][0][0];
  red[tid] = mloc;
  __syncthreads();
  for (int st = 256; st > 0; st >>= 1) {
    if (tid < st) red[tid] = fmaxf(red[tid], red[tid + st]);
    __syncthreads();
  }
  if (tid == 0) atomicMax(amax, __builtin_bit_cast(unsigned, red[0]));
}

// ---------------- f64 x@W (32x64 tiles); TX = float/double; optional row-gather*val ----------------

template <typename TX, int GATHER>
__global__ __launch_bounds__(256) void k_gemm_xw32(
    const TX* __restrict__ X, const int* __restrict__ perm, const double* __restrict__ vals,
    const float* __restrict__ W, double* __restrict__ C,
    int M, int N, int K, unsigned* __restrict__ rst) {
  if (blockIdx.x == 0 && blockIdx.y == 0 && threadIdx.x == 0 && threadIdx.y == 0 && rst) *rst = 0u;
  __shared__ double As[16][32];
  __shared__ double Bs[16][64];
  const int tx = threadIdx.x, ty = threadIdx.y;
  const int tid = ty * 16 + tx;
  const int brow = blockIdx.y * 32, bcol = blockIdx.x * 64;
  const int lac = tid & 15, lar = tid >> 4;
  const int lbc = tid & 63, lbr = tid >> 6;

  int srow[2];
  double sval[2];
#pragma unroll
  for (int rr = 0; rr < 2; ++rr) {
    int gr = brow + lar + rr * 16;
    if (GATHER) {
      srow[rr] = (gr < M) ? perm[gr] : 0;
      sval[rr] = (gr < M) ? vals[gr] : 0.0;
    } else {
      srow[rr] = gr;
      sval[rr] = 1.0;
    }
  }

  double acc[2][4];
#pragma unroll
  for (int i = 0; i < 2; ++i)
#pragma unroll
    for (int j = 0; j < 4; ++j) acc[i][j] = 0.0;

  for (int kt = 0; kt < K; kt += 16) {
#pragma unroll
    for (int rr = 0; rr < 2; ++rr) {
      int gr = brow + lar + rr * 16;
      int gk = kt + lac;
      double v = 0.0;
      if (gr < M && gk < K) {
        v = (double)X[(size_t)srow[rr] * K + gk];
        if (GATHER) v *= sval[rr];
      }
      As[lac][lar + rr * 16] = v;
    }
#pragma unroll
    for (int rr = 0; rr < 4; ++rr) {
      int br = lbr + rr * 4;
      int gk = kt + br, gc = bcol + lbc;
      Bs[br][lbc] = (gk < K && gc < N) ? (double)W[(size_t)gk * N + gc] : 0.0;
    }
    __syncthreads();
#pragma unroll
    for (int kk = 0; kk < 16; ++kk) {
      double a[2], b[4];
#pragma unroll
      for (int i = 0; i < 2; ++i) a[i] = As[kk][ty * 2 + i];
#pragma unroll
      for (int j = 0; j < 4; ++j) b[j] = Bs[kk][tx * 4 + j];
#pragma unroll
      for (int i = 0; i < 2; ++i)
#pragma unroll
        for (int j = 0; j < 4; ++j) acc[i][j] = fma(a[i], b[j], acc[i][j]);
    }
    __syncthreads();
  }
#pragma unroll
  for (int i = 0; i < 2; ++i) {
    int gr = brow + ty * 2 + i;
    if (gr >= M) continue;
#pragma unroll
    for (int j = 0; j < 4; ++j) {
      int gc = bcol + tx * 4 + j;
      if (gc >= N) continue;
      C[(size_t)gr * N + gc] = acc[i][j];
    }
  }
}

// ---------------- digit machinery (i8, base-128) ----------------

__global__ void k_wmax(const double* __restrict__ t, const double* __restrict__ dinv,
                       unsigned* __restrict__ wmax, int K, int N) {
  __shared__ float red[256];
  float mx = 0.0f;
  int tot = K * N;
  for (int i = blockIdx.x * 256 + threadIdx.x; i < tot; i += gridDim.x * 256) {
    double w = dinv[i / N] * t[i];
    mx = fmaxf(mx, (float)fabs(w));
  }
  red[threadIdx.x] = mx;
  __syncthreads();
  for (int st = 128; st > 0; st >>= 1) {
    if (threadIdx.x < st) red[threadIdx.x] = fmaxf(red[threadIdx.x], red[threadIdx.x + st]);
    __syncthreads();
  }
  if (threadIdx.x == 0) atomicMax(wmax, __builtin_bit_cast(unsigned, red[0]));
}

template <int D>
__global__ __launch_bounds__(256) void k_digitize8(
    const double* __restrict__ t, const double* __restrict__ dinv,
    const unsigned* __restrict__ wmax, char* __restrict__ wdT,
    int K, int Kpad, int N) {
  __shared__ char sm[D][64][68];
  const int tid = threadIdx.x;
  const int k0 = blockIdx.x * 64, n0 = blockIdx.y * 64;
  float wm = __builtin_bit_cast(float, *wmax);
  double sc = (wm > 0.0f) ? scalbn(1.0, -(ilogbf(wm) + 2)) : 0.0;
  const int kk = tid >> 2, ns = (tid & 3) * 16;
  int k = k0 + kk;
  double dv = (k < K) ? dinv[k] : 0.0;
#pragma unroll
  for (int j = 0; j < 16; ++j) {
    int n = n0 + ns + j;
    double w = (k < K) ? dv * t[(size_t)k * N + n] : 0.0;
    double r = w * sc;
#pragma unroll
    for (int d = 0; d < D; ++d) {
      double rm = r * 128.0;
      double m = rint(rm);
      sm[d][kk][ns + j] = (char)(int)m;
      r = rm - m;
    }
  }
  __syncthreads();
  const int nn = tid >> 2, ks = (tid & 3) * 16;
  const size_t PS = (size_t)N * Kpad;
#pragma unroll
  for (int d = 0; d < D; ++d) {
    char o[16];
#pragma unroll
    for (int j = 0; j < 16; ++j) o[j] = sm[d][ks + j][nn];
    *(int4*)&wdT[d * PS + (size_t)(n0 + nn) * Kpad + k0 + ks] = *(int4*)&o[0];
  }
}

// A3p f32 (nonneg, values-path) -> scaled 14-bit base-128 i8 planes.
__global__ void k_splitA8s(const float* __restrict__ A, int M, int ldsrc,
                           const unsigned* __restrict__ amax,
                           char* __restrict__ S, int Kpad) {
  int r = blockIdx.x;
  const size_t plane = (size_t)Kpad * Kpad;
  float am = __builtin_bit_cast(float, *amax);
  float s13 = (am > 0.0f) ? scalbnf(1.0f, 13 - (ilogbf(am) + 1)) : 0.0f;
  for (int c4 = threadIdx.x * 4; c4 < Kpad; c4 += blockDim.x * 4) {
    float v[4] = {0.f, 0.f, 0.f, 0.f};
    if (r < M && c4 < ldsrc) *(float4*)v = *(const float4*)(A + (size_t)r * ldsrc + c4);
    unsigned hw = 0, lw = 0;
#pragma unroll
    for (int q = 0; q < 4; ++q) {
      int iv = (int)rintf(v[q] * s13);
      int h = iv >> 7, l = iv - (h << 7);
      hw |= ((unsigned)(unsigned char)(char)h) << (8 * q);
      lw |= ((unsigned)(unsigned char)(char)l) << (8 * q);
    }
    *(unsigned*)(S + (size_t)r * Kpad + c4) = hw;
    *(unsigned*)(S + plane + (size_t)r * Kpad + c4) = lw;
  }
}

// P[Mp][Neff] i32 = A @ wdT^T — 2-buffer DMA-pipelined i8 GEMM, exact.
__global__ __launch_bounds__(256) void k_axw_pipe8(
    const char* __restrict__ Asrc, const char* __restrict__ Bsrc,
    int Kpad, int* __restrict__ P, int Neff)
{
  __shared__ __align__(16) char Ls[2][2][8192];
  const int tid = threadIdx.x;
  const int wave = tid >> 6, lane = tid & 63;
  const int wr = wave >> 1, wc = wave & 1;
  const int brow = blockIdx.y * 128, bcol = blockIdx.x * 128;
  const int lr = lane & 15, ko = (lane >> 4) * 16;
  const int koff = (lane & 3) * 16;

  const char* pA[2];
  const char* pB[2];
#pragma unroll
  for (int c = 0; c < 2; ++c) {
    int r = (c * 4 + wave) * 16 + (lane >> 2);
    pA[c] = Asrc + (size_t)(brow + r) * Kpad;
    pB[c] = Bsrc + (size_t)(bcol + r) * Kpad;
  }

  i32x4 acc[4][4];
#pragma unroll
  for (int m = 0; m < 4; ++m)
#pragma unroll
    for (int n = 0; n < 4; ++n) acc[m][n] = (i32x4){0, 0, 0, 0};

  auto STAGE = [&](int buf, int kt) {
#pragma unroll
    for (int c = 0; c < 2; ++c) {
      int f = c * 4 + wave;
      gl2lds16(pA[c] + kt + koff, &Ls[buf][0][f * 1024]);
      gl2lds16(pB[c] + kt + koff, &Ls[buf][1][f * 1024]);
    }
  };

  STAGE(0, 0);
  __syncthreads();
  int cur = 0;
  for (int kt = 0; kt < Kpad; kt += 64) {
    if (kt + 64 < Kpad) STAGE(cur ^ 1, kt + 64);
    i32x4 a0[4], b0[4];
#pragma unroll
    for (int m = 0; m < 4; ++m) a0[m] = *(const i32x4*)&Ls[cur][0][(wr * 64 + m * 16 + lr) * 64 + ko];
#pragma unroll
    for (int n = 0; n < 4; ++n) b0[n] = *(const i32x4*)&Ls[cur][1][(wc * 64 + n * 16 + lr) * 64 + ko];
#pragma unroll
    for (int m = 0; m < 4; ++m)
#pragma unroll
      for (int n = 0; n < 4; ++n)
        acc[m][n] = __builtin_amdgcn_mfma_i32_16x16x64_i8(a0[m], b0[n], acc[m][n], 0, 0, 0);
    __syncthreads();
    cur ^= 1;
  }

#pragma unroll
  for (int m = 0; m < 4; ++m)
#pragma unroll
    for (int n = 0; n < 4; ++n)
#pragma unroll
      for (int q = 0; q < 4; ++q) {
        int grow = brow + wr * 64 + m * 16 + (lane >> 4) * 4 + q;
        int gcol = bcol + wc * 64 + n * 16 + lr;
        P[(size_t)grow * Neff + gcol] = acc[m][n][q];
      }
}

// fused reduce_y + gcn_fin (+ optional per-row scores, + optional f32 output with tail zero)
template <int SCORES, int OUT32>
__global__ void k_reduce_fin(const int* __restrict__ P, const unsigned* __restrict__ wmax,
                             const unsigned* __restrict__ amax,
                             const double* __restrict__ t, const double* __restrict__ dinv,
                             const float* __restrict__ bias, double* __restrict__ out,
                             float* __restrict__ fout, int nvals, int total,
                             const float* __restrict__ p, double* __restrict__ scv,
                             unsigned* __restrict__ rst,
                             int Neff, int N, int D, int M0pad, int nplane,
                             double w0, double w1, int relu) {
  int m = blockIdx.x;
  if (SCORES) { if (m == 0 && threadIdx.x == 0 && rst) *rst = 0u; }
  float wm = __builtin_bit_cast(float, *wmax);
  double s0 = w0, s1 = w1;
  bool zero = (wm <= 0.0f);
  if (amax) {
    float am = __builtin_bit_cast(float, *amax);
    if (am > 0.0f) {
      int EA = ilogbf(am) + 1;
      s0 = scalbn(w0, EA - 13);
      s1 = scalbn(w1, EA - 13);
    } else zero = true;
  }
  int Ep = zero ? 0 : (ilogbf(wm) + 2);
  double d = dinv[m];
  __shared__ double red[256], red2[256];
  double sdot = 0.0, sp2 = 0.0;
  for (int n = threadIdx.x; n < N; n += blockDim.x) {
    double acc = 0.0;
    if (!zero) {
      for (int dd = 0; dd < D; ++dd) {
        double v = s0 * (double)P[(size_t)m * Neff + dd * N + n];
        if (nplane == 2) v += s1 * (double)P[(size_t)(M0pad + m) * Neff + dd * N + n];
        acc += scalbn(v, Ep - 7 * (dd + 1));
      }
    }
    double v = d * (acc + 2.0 * d * t[(size_t)m * N + n]) + (double)bias[n];
    if (relu) v = v > 0.0 ? v : 0.0;
    if (OUT32) fout[(size_t)m * N + n] = (float)v;
    else out[(size_t)m * N + n] = v;
    if (SCORES) {
      double pv = (double)p[n];
      sdot += v * pv;
      sp2 += pv * pv;
    }
  }
  if (OUT32) {
    if (m == 0)
      for (int i = nvals + threadIdx.x; i < total; i += blockDim.x) fout[i] = 0.0f;
  }
  if (SCORES) {
    red[threadIdx.x] = sdot;
    red2[threadIdx.x] = sp2;
    __syncthreads();
    for (int st = 128; st > 0; st >>= 1) {
      if (threadIdx.x < st) {
        red[threadIdx.x] += red[threadIdx.x + st];
        red2[threadIdx.x] += red2[threadIdx.x + st];
      }
      __syncthreads();
    }
    if (threadIdx.x == 0) scv[m] = tanh(red[0] / sqrt(red2[0]));
  }
}

// ---------------- GCN tail / pooling ----------------

template <typename TA>
__device__ __forceinline__ float a_as_f32(TA v);
template <> __device__ __forceinline__ float a_as_f32<char>(char v) { return (float)v; }
template <> __device__ __forceinline__ float a_as_f32<float>(float v) { return v; }

template <typename TA>
__global__ void k_degdinv(const TA* __restrict__ A, int lda, double* __restrict__ dinv, int n,
                          unsigned* __restrict__ rst0, unsigned* __restrict__ rst1) {
  if (blockIdx.x == 0 && threadIdx.x == 0) {
    if (rst0) *rst0 = 0u;
    if (rst1) *rst1 = 0u;
  }
  __shared__ double red[256];
  int row = blockIdx.x;
  double s = 0.0;
  for (int j = threadIdx.x; j < n; j += 256) s += (double)a_as_f32<TA>(A[(size_t)row * lda + j]);
  red[threadIdx.x] = s;
  __syncthreads();
  for (int st = 128; st > 0; st >>= 1) {
    if (threadIdx.x < st) red[threadIdx.x] += red[threadIdx.x + st];
    __syncthreads();
  }
  if (threadIdx.x == 0) {
    double deg = red[0] + 2.0;
    dinv[row] = (deg > 0.0) ? 1.0 / sqrt(deg) : 0.0;
  }
}

// dinv from 2-plane i8 (128*h + l): exact integer row sums.
__global__ void k_degdinv2p(const char* __restrict__ S, int Kpad, double* __restrict__ dinv,
                            int n, unsigned* __restrict__ rst0) {
  if (blockIdx.x == 0 && threadIdx.x == 0 && rst0) *rst0 = 0u;
  __shared__ double red[256];
  const size_t plane = (size_t)Kpad * Kpad;
  int row = blockIdx.x;
  const char* h = S + (size_t)row * Kpad;
  const char* l = S + plane + (size_t)row * Kpad;
  long s = 0;
  for (int j = threadIdx.x; j < n; j += 256) s += 128 * (long)h[j] + (long)l[j];
  red[threadIdx.x] = (double)s;
  __syncthreads();
  for (int st = 128; st > 0; st >>= 1) {
    if (threadIdx.x < st) red[threadIdx.x] += red[threadIdx.x + st];
    __syncthreads();
  }
  if (threadIdx.x == 0) {
    double deg = red[0] + 2.0;
    dinv[row] = (deg > 0.0) ? 1.0 / sqrt(deg) : 0.0;
  }
}

// rank-count top-k (bitwise-identical to full sort under (score desc, idx asc))
__global__ __launch_bounds__(256) void k_topk_rank(
    const double* __restrict__ sc, int n, int k,
    int* __restrict__ perm, double* __restrict__ vals) {
  __shared__ int red[256];
  const int i = blockIdx.x;
  const double si = sc[i];
  int cnt = 0;
  for (int j = threadIdx.x; j < n; j += 256) {
    double sj = sc[j];
    if (sj > si || (sj == si && j < i)) ++cnt;
  }
  red[threadIdx.x] = cnt;
  __syncthreads();
  for (int st = 128; st > 0; st >>= 1) {
    if (threadIdx.x < st) red[threadIdx.x] += red[threadIdx.x + st];
    __syncthreads();
  }
  if (threadIdx.x == 0) {
    int rank = red[0];
    if (rank < k) { perm[rank] = i; vals[rank] = si; }
  }
}

__global__ void k_sentinel(float* __restrict__ out, int total) {
  int i = blockIdx.x * blockDim.x + threadIdx.x;
  int st = gridDim.x * blockDim.x;
  for (; i < total; i += st) out[i] = 1e30f;
}

// ---------------- driver ----------------

extern "C" void kernel_launch(void* const* d_in, const int* in_sizes, int n_in,
                              void* d_out, int out_size, void* d_ws, size_t ws_size,
                              hipStream_t stream) {
  const float* x0f  = (const float*)d_in[0];
  const int*   ei   = (const int*)d_in[1];
  const float* W0   = (const float*)d_in[2];
  const float* b0   = (const float*)d_in[3];
  const float* W1   = (const float*)d_in[4];
  const float* b1   = (const float*)d_in[5];
  const float* W2   = (const float*)d_in[6];
  const float* b2   = (const float*)d_in[7];
  const float* p1   = (const float*)d_in[8];
  const float* p2   = (const float*)d_in[9];
  const float* Wout = (const float*)d_in[10];
  const float* bout = (const float*)d_in[11];
  const int E = in_sizes[1] / 2;

  const size_t MiB = 1ull << 20;
  if (ws_size < 160 * MiB) {
    k_sentinel<<<dim3(256), dim3(256), 0, stream>>>((float*)d_out, out_size);
    return;
  }
  char* W = (char*)d_ws;
  const size_t PL2 = (size_t)KI2 * KI2;
  // epoch A: build + aug1 (A0 built directly as i8)
  char*  A0s8  = (char*)(W + 64 * MiB);
  char*  A0s8T = (char*)(W + 80 * MiB);
  // epoch A2: gcn1
  char*  A1    = (char*)(W + 0);
  char*  A1T   = (char*)(W + 16 * MiB);
  char*  wdT1  = (char*)(W + 32 * MiB);
  int*   P1    = (int*)(W + 40 * MiB);
  // epoch B: aug2 + gcn2
  char*  A2s8  = (char*)(W + 64 * MiB);
  char*  A2s8T = (char*)(W + 86 * MiB);
  char*  wdT2  = (char*)(W + 0);
  int*   P2    = (int*)(W + 7 * MiB);
  // epoch C: aug3 + gcn3/out
  float* A3p     = (float*)(W + 108 * MiB);
  char*  A3stack = (char*)(W + 0);
  char*  wdT3    = (char*)(W + 8 * MiB);
  int*   P3      = (int*)(W + 10 * MiB);
  // features
  double* tb   = (double*)(W + 128 * MiB);
  double* xA   = (double*)(W + 144 * MiB);
  char* SM = W + (159 * MiB + 256 * 1024);
  double* dinv = (double*)(SM);
  double* sc   = (double*)(SM + 32768);
  double* vals = (double*)(SM + 65536);
  unsigned* wmax  = (unsigned*)(SM + 98304 + 128);
  unsigned* a3max = (unsigned*)(SM + 98304 + 192);
  int* perm    = (int*)(SM + 98304 + 256);
  int* permB   = (int*)(SM + 98304 + 256 + 16384);
  char* zpage  = (char*)(W + 159 * MiB + 512 * 1024);

  // ---- build A0 as i8 + transpose (+2I) ----
  k_zero32<<<dim3(8), dim3(256), 0, stream>>>((float*)zpage, 8192);
  k_zero32<<<dim3(1024), dim3(256), 0, stream>>>((float*)A0s8, (size_t)N0 * N0 / 4);
  k_build_adj8<<<dim3((E + 255) / 256), dim3(256), 0, stream>>>(ei, (unsigned*)A0s8, E, N0);
  k_transpose_i8s<<<dim3(64, 64, 1), dim3(256), 0, stream>>>(A0s8, A0s8T, N0, 0, 2, 0);

  // ---- aug1 ----
  k_aug_pipe8<0><<<dim3(32, 32), dim3(256), 0, stream>>>(
      A0s8, A0s8T, nullptr, zpage, N0, N0, A1, 0, N0, N0, N0);
  k_transpose_i8s<<<dim3(64, 64, 1), dim3(256), 0, stream>>>(A1, A1T, N0, 0, 2, 0);

  // ---- gcn1 ----
  {
    dim3 b(16, 16);
    k_gemm_xw32<float, 0><<<dim3(HID / 64, (N0 + 31) / 32), b, 0, stream>>>(
        x0f, nullptr, nullptr, W0, tb, N0, HID, CIN, nullptr);
    k_degdinv<char><<<dim3(N0), dim3(256), 0, stream>>>(A1, N0, dinv, N0, wmax, nullptr);
    k_wmax<<<dim3(256), dim3(256), 0, stream>>>(tb, dinv, wmax, N0, HID);
    k_digitize8<DNUM><<<dim3(N0 / 64, HID / 64), dim3(256), 0, stream>>>(tb, dinv, wmax, wdT1, N0, N0, HID);
    k_axw_pipe8<<<dim3(DNUM * HID / 128, N0 / 128), dim3(256), 0, stream>>>(A1, wdT1, N0, P1, DNUM * HID);
    k_reduce_fin<1, 0><<<dim3(N0), dim3(256), 0, stream>>>(
        P1, wmax, nullptr, tb, dinv, b0, xA, nullptr, 0, 0, p1, sc, nullptr,
        DNUM * HID, HID, DNUM, 0, 1, 1.0, 0.0, 1);
  }

  // ---- pool1 ----
  k_topk_rank<<<dim3(N0), dim3(256), 0, stream>>>(sc, N0, K1P, perm, vals);

  // ---- aug2 ----
  k_aug_pipe8<1><<<dim3(26, 26), dim3(256), 0, stream>>>(
      A1, A1T, perm, zpage, N0, N0, A2s8, PL2, KI2, K1P, K1P);
  k_transpose_i8s<<<dim3(52, 52, 2), dim3(256), 0, stream>>>(A2s8, A2s8T, KI2, PL2, 0, 2);

  // ---- gcn2 ----
  {
    dim3 b(16, 16);
    k_gemm_xw32<double, 1><<<dim3(HID / 64, (K1P + 31) / 32), b, 0, stream>>>(
        xA, perm, vals, W1, tb, K1P, HID, HID, nullptr);
    k_degdinv2p<<<dim3(K1P), dim3(256), 0, stream>>>(A2s8, KI2, dinv, K1P, wmax);
    k_wmax<<<dim3(256), dim3(256), 0, stream>>>(tb, dinv, wmax, K1P, HID);
    k_digitize8<DNUM><<<dim3(KI2 / 64, HID / 64), dim3(256), 0, stream>>>(tb, dinv, wmax, wdT2, K1P, KI2, HID);
    k_axw_pipe8<<<dim3(DNUM * HID / 128, 2 * KI2 / 128), dim3(256), 0, stream>>>(A2s8, wdT2, KI2, P2, DNUM * HID);
    k_reduce_fin<1, 0><<<dim3(K1P), dim3(256), 0, stream>>>(
        P2, wmax, nullptr, tb, dinv, b1, xA, nullptr, 0, 0, p2, sc, a3max,
        DNUM * HID, HID, DNUM, KI2, 2, 128.0, 1.0, 1);
  }

  // ---- pool2 ----
  k_topk_rank<<<dim3(K1P), dim3(256), 0, stream>>>(sc, K1P, K2P, permB, vals);

  // ---- aug3 ----
  k_aug3_pipe8<<<dim3(16, 16), dim3(512), 0, stream>>>(
      A2s8, A2s8T, permB, zpage, KI2, A3p, a3max, K2P, K2P, LD3);

  // ---- gcn3 ----
  {
    dim3 b(16, 16);
    k_gemm_xw32<double, 1><<<dim3(HID / 64, (K2P + 31) / 32), b, 0, stream>>>(
        xA, permB, vals, W2, tb, K2P, HID, HID, nullptr);
    k_degdinv<float><<<dim3(K2P), dim3(256), 0, stream>>>(A3p, LD3, dinv, K2P, wmax, nullptr);
    k_splitA8s<<<dim3(KI3), dim3(256), 0, stream>>>(A3p, K2P, LD3, a3max, A3stack, KI3);
    k_wmax<<<dim3(256), dim3(256), 0, stream>>>(tb, dinv, wmax, K2P, HID);
    k_digitize8<2><<<dim3(KI3 / 64, HID / 64), dim3(256), 0, stream>>>(tb, dinv, wmax, wdT3, K2P, KI3, HID);
    k_axw_pipe8<<<dim3(2 * HID / 128, 2 * KI3 / 128), dim3(256), 0, stream>>>(A3stack, wdT3, KI3, P3, 2 * HID);
    k_reduce_fin<0, 0><<<dim3(K2P), dim3(256), 0, stream>>>(
        P3, wmax, a3max, tb, dinv, b2, xA, nullptr, 0, 0, nullptr, nullptr, nullptr,
        2 * HID, HID, 2, KI3, 2, 128.0, 1.0, 1);
  }

  // ---- gcn_out ----
  {
    dim3 b(16, 16);
    k_gemm_xw32<double, 0><<<dim3(COUTC / 64, (K2P + 31) / 32), b, 0, stream>>>(
        xA, nullptr, nullptr, Wout, tb, K2P, COUTC, HID, wmax);
    k_wmax<<<dim3(256), dim3(256), 0, stream>>>(tb, dinv, wmax, K2P, COUTC);
    k_digitize8<2><<<dim3(KI3 / 64, COUTC / 64), dim3(256), 0, stream>>>(tb, dinv, wmax, wdT3, K2P, KI3, COUTC);
    k_axw_pipe8<<<dim3(2 * COUTC / 128, 2 * KI3 / 128), dim3(256), 0, stream>>>(A3stack, wdT3, KI3, P3, 2 * COUTC);
    k_reduce_fin<0, 1><<<dim3(K2P), dim3(256), 0, stream>>>(
        P3, wmax, a3max, tb, dinv, bout, nullptr, (float*)d_out, K2P * COUTC, out_size,
        nullptr, nullptr, nullptr, 2 * COUTC, COUTC, 2, KI3, 2, 128.0, 1.0, 0);
  }
}